// Round 18
// baseline (792.683 us; speedup 1.0000x reference)
//
#include <hip/hip_runtime.h>

#define BATCH 65536

typedef __attribute__((ext_vector_type(8))) short bf16x8;
typedef __attribute__((ext_vector_type(4))) float f32x4;

__device__ __forceinline__ unsigned short f2bf(float f) {
  unsigned int u = __float_as_uint(f);
  u += 0x7fffu + ((u >> 16) & 1u);   // RNE (one-time weight builds only)
  return (unsigned short)(u >> 16);
}
// trunc-pack 2 floats -> 1 dword of 2 bf16 (lo in low half), single v_perm_b32
__device__ __forceinline__ unsigned pack_trunc(float lo, float hi) {
  return __builtin_amdgcn_perm(__float_as_uint(hi), __float_as_uint(lo), 0x07060302u);
}

// tanh(o)*sigmoid(u): 2 exp + 1 rcp; lower-bound clamps keep it NaN-proof.
__device__ __forceinline__ float gru_act(float u, float o) {
  u = fmaxf(u, -60.0f);
  o = fmaxf(o, -30.0f);
  float a  = __expf(-u);
  float a2 = __expf(-2.0f * o);
  return (1.0f - a2) * __builtin_amdgcn_rcpf((1.0f + a) * (1.0f + a2));
}

// conv 3x3 SAME on 3x3 grid, unrolled tap value
__device__ __forceinline__ float conv_tap(const float* __restrict__ w, int co, int ci,
                                          int p, int q, int CINTOT) {
  int pi = p / 3, pj = p % 3, qi = q / 3, qj = q % 3;
  int di = qi - pi + 1, dj = qj - pj + 1;
  if ((unsigned)di < 3u && (unsigned)dj < 3u)
    return w[((co * CINTOT + ci) * 3 + di) * 3 + dj];
  return 0.0f;
}

// Frag-major builders: lane = jc*16 + (n&15) holds B[n][kt*32 + jc*8 + s].
__global__ void build_bt2f(const float* __restrict__ wu, const float* __restrict__ wo,
                           unsigned short* __restrict__ BTF) {
  int e = blockIdx.x * 256 + threadIdx.x;
  if (e >= 331776) return;
  int g = e / 165888;
  int rem = e - g * 165888;
  int n = rem / 288, k = rem - n * 288;
  int cf = n >> 4, lr = n & 15, kt = k >> 5, jc = (k >> 3) & 3, s = k & 7;
  unsigned dst = ((((unsigned)(g * 36 + cf) * 9 + kt) * 64 + jc * 16 + lr) * 8 + s);
  BTF[dst] = f2bf(conv_tap(g ? wo : wu, n / 9, k / 9, n % 9, k % 9, 96));
}
__global__ void build_bt3f(const float* __restrict__ wu, const float* __restrict__ wo,
                           unsigned short* __restrict__ BTF) {
  int e = blockIdx.x * 256 + threadIdx.x;
  if (e >= 165888) return;
  int g = e / 82944;
  int rem = e - g * 82944;
  int n = rem / 576, k = rem - n * 576;
  int cf = n >> 4, lr = n & 15, kt = k >> 5, jc = (k >> 3) & 3, s = k & 7;
  unsigned dst = ((((unsigned)(g * 9 + cf) * 18 + kt) * 64 + jc * 16 + lr) * 8 + s);
  BTF[dst] = f2bf(conv_tap(g ? wo : wu, n / 9, k / 9, n % 9, k % 9, 80));
}
__global__ void build_bt1f(const float* __restrict__ wu, const float* __restrict__ wo,
                           unsigned short* __restrict__ BTF) {
  int e = blockIdx.x * 256 + threadIdx.x;
  if (e >= 18432) return;
  int g = e / 9216;
  int rem = e - g * 9216;
  int n = rem / 32, k = rem - n * 32;
  int cf = n >> 4, lr = n & 15, jc = (k >> 3) & 3, s = k & 7;
  unsigned dst = (((unsigned)(g * 18 + cf) * 64 + jc * 16 + lr) * 8 + s);
  float v = (k < 9) ? conv_tap(g ? wo : wu, n / 9, 0, n % 9, k, 33) : 0.0f;
  BTF[dst] = f2bf(v);
}

// ---------------- LDS layout (bytes), lifetimes barrier-separated ----------------
// Total 40960 B -> 4 blocks/CU (4 x 40960 = 163840 = full 160 KiB pool).
// [0,40960)     x1l 64x640 (L1 epi .. L2 reads)
//   overlays: xl2 [0,9216) (input staging, DEAD before first x1l write — extra
//             barrier after afx reads); x3l [0,18688) (L3 epi .. dense);
//             wl [20480,25664) + blb [25664,25700) (post-L2 .. dense)
#define OFF_X1L 0
#define OFF_X3L 0
#define OFF_XL2 0
#define OFF_WL 20480
#define OFF_BLB 25664
#define SMEM_BYTES 40960

// One L1 chunk: MFMA from register B frags, fused activation epilogue.
#define L1_CHUNK(BREG, CH) do {                                              \
    f32x4 acc1[4][2][3] = {};                                                \
    _Pragma("unroll") for (int m_ = 0; m_ < 4; ++m_)                         \
      _Pragma("unroll") for (int g_ = 0; g_ < 2; ++g_)                       \
        _Pragma("unroll") for (int f_ = 0; f_ < 3; ++f_)                     \
          acc1[m_][g_][f_] = __builtin_amdgcn_mfma_f32_16x16x32_bf16(        \
              afx[m_], BREG[g_][f_], acc1[m_][g_][f_], 0, 0, 0);             \
    _Pragma("unroll") for (int m_ = 0; m_ < 4; ++m_)                         \
      _Pragma("unroll") for (int f_ = 0; f_ < 3; ++f_) {                     \
        int n_ = (CH) * 144 + (wid * 3 + f_) * 16 + lrow;                    \
        float bU_ = b1u[n_ / 9], bO_ = b1o[n_ / 9];                          \
        f32x4 uv_ = acc1[m_][0][f_], ov_ = acc1[m_][1][f_];                  \
        _Pragma("unroll") for (int t_ = 0; t_ < 4; ++t_) {                   \
          int r_ = m_ * 16 + jc * 4 + t_;                                    \
          float v_ = gru_act(uv_[t_] + bU_, ov_[t_] + bO_);                  \
          x1[(size_t)(r0 + r_) * 288 + n_] = v_;                             \
          *(unsigned short*)(x1l + r_ * 640 + (((n_ >> 3) ^ (r_ & 7)) << 4) + (n_ & 7) * 2) = \
              (unsigned short)(__float_as_uint(v_) >> 16);                   \
        }                                                                    \
      }                                                                      \
  } while (0)

// One L2 K-step: MFMA on CUR reg B-frags; prefetch next step's frags into NXT.
#define L2_STEP(CUR, NXT, LAST) do {                                         \
    if (!(LAST)) {                                                           \
      _Pragma("unroll") for (int g_ = 0; g_ < 2; ++g_)                       \
        _Pragma("unroll") for (int f_ = 0; f_ < 3; ++f_)                     \
          NXT[g_][f_] = *(const bf16x8*)(BT2b + ldoff + offB2[g_][f_]);      \
      if (ktn == 8) { ktn = 0; ldoff += 102400u; }                           \
      else { ++ktn; ldoff += 1024u; }                                        \
    }                                                                        \
    bf16x8 af_[4];                                                           \
    const int c8_ = kt * 4 + jc;                                             \
    _Pragma("unroll") for (int m_ = 0; m_ < 4; ++m_)                         \
      af_[m_] = *(const bf16x8*)(aBase[m_] + ((c8_ ^ aXor[m_]) << 4));       \
    _Pragma("unroll") for (int m_ = 0; m_ < 4; ++m_)                         \
      _Pragma("unroll") for (int g_ = 0; g_ < 2; ++g_)                       \
        _Pragma("unroll") for (int f_ = 0; f_ < 3; ++f_)                     \
          acc[m_][g_][f_] = __builtin_amdgcn_mfma_f32_16x16x32_bf16(         \
              af_[m_], CUR[g_][f_], acc[m_][g_][f_], 0, 0, 0);               \
    if (kt == 8) {                                                           \
      _Pragma("unroll") for (int m_ = 0; m_ < 4; ++m_)                       \
        _Pragma("unroll") for (int f_ = 0; f_ < 3; ++f_) {                   \
          int n_ = n0 + (wid * 3 + f_) * 16 + lrow;                          \
          float bU_ = b2u[n_ / 9], bO_ = b2o[n_ / 9];                        \
          f32x4 uv_ = acc[m_][0][f_], ov_ = acc[m_][1][f_];                  \
          _Pragma("unroll") for (int t_ = 0; t_ < 4; ++t_) {                 \
            int r_ = r0 + m_ * 16 + jc * 4 + t_;                             \
            x2[(size_t)r_ * 576 + n_] = gru_act(uv_[t_] + bU_, ov_[t_] + bO_); \
          }                                                                  \
          acc[m_][0][f_] = (f32x4){0.f, 0.f, 0.f, 0.f};                      \
          acc[m_][1][f_] = (f32x4){0.f, 0.f, 0.f, 0.f};                      \
        }                                                                    \
      kt = 0; n0 += 192;                                                     \
    } else ++kt;                                                             \
  } while (0)

// One L3 K-step (r12/r15-proven): staged Al (2 barriers) + frag-major reg B.
#define L3_STEP(CURB, NXTB) do {                                             \
    {                                                                        \
      uint4 h_;                                                              \
      h_.x = pack_trunc(pa0.x, pa0.y);                                       \
      h_.y = pack_trunc(pa0.z, pa0.w);                                       \
      h_.z = pack_trunc(pa1.x, pa1.y);                                       \
      h_.w = pack_trunc(pa1.z, pa1.w);                                       \
      *(uint4*)wAl = h_;                                                     \
    }                                                                        \
    __syncthreads();   /* Al ready */                                        \
    if (kt3 < 17) {                                                          \
      const float* gp_ = pA + (kt3 + 1) * 32;                                \
      pa0 = *(const float4*)gp_;                                             \
      pa1 = *(const float4*)(gp_ + 4);                                       \
      if (wid < 3) {                                                         \
        _Pragma("unroll") for (int g_ = 0; g_ < 2; ++g_)                     \
          _Pragma("unroll") for (int f_ = 0; f_ < 3; ++f_)                   \
            NXTB[g_][f_] = *(const bf16x8*)(BT3b + b3ld + offB3[g_][f_]);    \
      }                                                                      \
      b3ld += 1024u;                                                         \
    }                                                                        \
    if (wid < 3) {                                                           \
      bf16x8 af_[4];                                                         \
      _Pragma("unroll") for (int m_ = 0; m_ < 4; ++m_)                       \
        af_[m_] = *(const bf16x8*)(rA3[m_]);                                 \
      _Pragma("unroll") for (int m_ = 0; m_ < 4; ++m_)                       \
        _Pragma("unroll") for (int g_ = 0; g_ < 2; ++g_)                     \
          _Pragma("unroll") for (int f_ = 0; f_ < 3; ++f_)                   \
            acc[m_][g_][f_] = __builtin_amdgcn_mfma_f32_16x16x32_bf16(       \
                af_[m_], CURB[g_][f_], acc[m_][g_][f_], 0, 0, 0);            \
    }                                                                        \
    __syncthreads();                                                         \
    ++kt3;                                                                   \
  } while (0)

__global__ __launch_bounds__(256, 4) void megafused(
    const float* __restrict__ xin, const unsigned short* __restrict__ BT1F,
    const float* __restrict__ b1u, const float* __restrict__ b1o,
    const unsigned short* __restrict__ BT2F,
    const float* __restrict__ b2u, const float* __restrict__ b2o,
    const unsigned short* __restrict__ BT3F,
    const float* __restrict__ b3u, const float* __restrict__ b3o,
    const float* __restrict__ wd, const float* __restrict__ bd,
    float* __restrict__ x1, float* __restrict__ x2,
    float* __restrict__ x3, float* __restrict__ out) {
  __shared__ __align__(16) char smem[SMEM_BYTES];
  char* x1l = smem + OFF_X1L;
  unsigned short* x3l = (unsigned short*)(smem + OFF_X3L);
  float* xl2 = (float*)(smem + OFF_XL2);    // overlays x1l[0,9216): dead pre-L1
  float* wl = (float*)(smem + OFF_WL);
  float* blb = (float*)(smem + OFF_BLB);

  const int tid = threadIdx.x;
  const int lane = tid & 63;
  const int wid = tid >> 6;
  const int lrow = lane & 15;
  const int jc = lane >> 4;
  const int r0 = blockIdx.x * 64;

  const char* BT1b = (const char*)BT1F;
  const char* BT2b = (const char*)BT2F;
  const char* BT3b = (const char*)BT3F;
  const unsigned laneB = (unsigned)lane * 16u;

  // per-thread frag-major byte offsets (wave reads its own cols, lane-contiguous)
  unsigned offB1[2][3], offB2[2][3], offB3[2][3];
#pragma unroll
  for (int g = 0; g < 2; ++g)
#pragma unroll
    for (int f = 0; f < 3; ++f) {
      offB1[g][f] = (unsigned)(g * 18 + wid * 3 + f) * 1024u + laneB;
      offB2[g][f] = (unsigned)(g * 36 + wid * 3 + f) * 9216u + laneB;
      offB3[g][f] = (unsigned)(g * 9 + wid * 3 + f) * 18432u + laneB;
    }

  // issue L1 B loads (both chunks) + L2 step-0 B loads; in flight over staging
  bf16x8 b1a[2][3], b1b[2][3], bX[2][3], bY[2][3];
  if (wid < 3) {
#pragma unroll
    for (int g = 0; g < 2; ++g)
#pragma unroll
      for (int f = 0; f < 3; ++f) {
        b1a[g][f] = *(const bf16x8*)(BT1b + offB1[g][f]);
        b1b[g][f] = *(const bf16x8*)(BT1b + 9216u + offB1[g][f]);
      }
  }
#pragma unroll
  for (int g = 0; g < 2; ++g)
#pragma unroll
    for (int f = 0; f < 3; ++f)
      bX[g][f] = *(const bf16x8*)(BT2b + offB2[g][f]);

  // stage x input into zero-padded xl2[64][36] (K padded 9->32)
  for (int c = tid; c < 2304; c += 256) {
    int row = c / 36, col = c - row * 36;
    xl2[c] = (col < 9) ? xin[(size_t)(r0 + row) * 9 + col] : 0.0f;
  }
  __syncthreads();   // xl2 visible

  // A-fragments for L1 (invariant across both chunks)
  bf16x8 afx[4];
#pragma unroll
  for (int m = 0; m < 4; ++m) {
    const float* xr = xl2 + (m * 16 + lrow) * 36 + jc * 8;
    float4 a0 = *(const float4*)xr;
    float4 a1 = *(const float4*)(xr + 4);
    union { uint4 u; bf16x8 v; } cv;
    cv.u.x = pack_trunc(a0.x, a0.y);
    cv.u.y = pack_trunc(a0.z, a0.w);
    cv.u.z = pack_trunc(a1.x, a1.y);
    cv.u.w = pack_trunc(a1.z, a1.w);
    afx[m] = cv.v;
  }
  __syncthreads();   // all xl2 reads done BEFORE x1l writes overlay the region

  // ---- L1: 2 chunks of 144 cols/gate, pure register B ----
  if (wid < 3) {
    L1_CHUNK(b1a, 0);
    L1_CHUNK(b1b, 1);
  }
  __syncthreads();   // x1l visible to all waves (LAST barrier before L2 loop)

  // ---- L2: x1l x BT2F(global->reg, coalesced frag loads). BARRIER-FREE ----
  {
    const char* aBase[4];
    int aXor[4];
#pragma unroll
    for (int m = 0; m < 4; ++m) {
      int row = m * 16 + lrow;
      aBase[m] = x1l + row * 640;
      aXor[m] = row & 7;
    }
    f32x4 acc[4][2][3] = {};
    int kt = 0, n0 = 0, ktn = 1;
    unsigned ldoff = 1024u;   // byte offset of step-1 tile (nch0, kt1)
    for (int sp = 0; sp < 13; ++sp) {
      L2_STEP(bX, bY, false);
      L2_STEP(bY, bX, false);
    }
    L2_STEP(bX, bY, true);    // step 26 (kt==8 -> final epilogue)
  }
  __syncthreads();   // x2 stores drained (vmcnt0); x1l dead beyond here

  // stage dense weights (overlay dead x1l region; disjoint from x3l)
  for (int c = tid; c < 1296; c += 256) wl[c] = wd[c];
  if (tid < 9) blb[tid] = bd[tid];

  // ---- L3: x2 (staged Al in x1l[25728..29824), 2 barriers) x BT3F reg B ----
  {
    char* Al = x1l + 25728;   // 64x64 = 4096 B, disjoint from x3l/wl/blb
    const float* pA = x2 + (size_t)(r0 + (tid >> 2)) * 576 + (tid & 3) * 8;
    char* wAl = Al + (tid >> 2) * 64 + (((tid & 3) ^ (((tid >> 2) >> 1) & 3)) << 4);
    float4 pa0 = *(const float4*)pA;
    float4 pa1 = *(const float4*)(pA + 4);
    bf16x8 b3a[2][3], b3b[2][3];
    if (wid < 3) {
#pragma unroll
      for (int g = 0; g < 2; ++g)
#pragma unroll
        for (int f = 0; f < 3; ++f)
          b3a[g][f] = *(const bf16x8*)(BT3b + offB3[g][f]);
    }
    const char* rA3[4];
#pragma unroll
    for (int m = 0; m < 4; ++m) {
      int row = m * 16 + lrow;
      rA3[m] = Al + row * 64 + ((jc ^ ((row >> 1) & 3)) << 4);
    }

    f32x4 acc[4][2][3] = {};
    int kt3 = 0;
    unsigned b3ld = 1024u;
    for (int kp = 0; kp < 9; ++kp) {
      L3_STEP(b3a, b3b);
      L3_STEP(b3b, b3a);
    }
    // epilogue: act -> x3 global fp32 + x3l (LDS bf16, trunc)
    if (wid < 3) {
#pragma unroll
      for (int m = 0; m < 4; ++m)
#pragma unroll
        for (int f = 0; f < 3; ++f) {
          int n = (wid * 3 + f) * 16 + lrow;
          float bU = b3u[n / 9], bO = b3o[n / 9];
          f32x4 uv = acc[m][0][f], ov = acc[m][1][f];
#pragma unroll
          for (int t = 0; t < 4; ++t) {
            int r = m * 16 + jc * 4 + t;
            float v = gru_act(uv[t] + bU, ov[t] + bO);
            x3[(size_t)(r0 + r) * 144 + n] = v;
            x3l[r * 146 + n] = (unsigned short)(__float_as_uint(v) >> 16);
          }
        }
    }
  }
  __syncthreads();   // x3l + wl ready

  // ---- dense head: 3 waves, 3 cols each ----
  if (wid < 3) {
    int drow = lane;
    int jb = wid * 3;
    float s0 = blb[jb], s1 = blb[jb + 1], s2 = blb[jb + 2];
    for (int k = 0; k < 144; k += 2) {
      unsigned pr = *(const unsigned*)&x3l[drow * 146 + k];
      float v0 = __uint_as_float(pr << 16);
      float v1 = __uint_as_float(pr & 0xffff0000u);
      const float2 w0 = *(const float2*)&wl[jb * 144 + k];
      const float2 w1 = *(const float2*)&wl[(jb + 1) * 144 + k];
      const float2 w2 = *(const float2*)&wl[(jb + 2) * 144 + k];
      s0 = fmaf(v0, w0.x, s0); s0 = fmaf(v1, w0.y, s0);
      s1 = fmaf(v0, w1.x, s1); s1 = fmaf(v1, w1.y, s1);
      s2 = fmaf(v0, w2.x, s2); s2 = fmaf(v1, w2.y, s2);
    }
    size_t ob = (size_t)(r0 + drow) * 9 + jb;
    out[ob] = s0; out[ob + 1] = s1; out[ob + 2] = s2;
  }
}

extern "C" void kernel_launch(void* const* d_in, const int* in_sizes, int n_in,
                              void* d_out, int out_size, void* d_ws, size_t ws_size,
                              hipStream_t stream) {
  const float* inputs = (const float*)d_in[0];
  const float* wd  = (const float*)d_in[1];
  const float* bd  = (const float*)d_in[2];
  const float* w1u = (const float*)d_in[3];
  const float* b1u = (const float*)d_in[4];
  const float* w1o = (const float*)d_in[7];
  const float* b1o = (const float*)d_in[8];
  const float* w2u = (const float*)d_in[9];
  const float* b2u = (const float*)d_in[10];
  const float* w2o = (const float*)d_in[13];
  const float* b2o = (const float*)d_in[14];
  const float* w3u = (const float*)d_in[15];
  const float* b3u = (const float*)d_in[16];
  const float* w3o = (const float*)d_in[19];
  const float* b3o = (const float*)d_in[20];

  float* out = (float*)d_out;                    // [B][9]
  float* x1 = out + (size_t)BATCH * 9;           // [B][288]
  float* x2 = x1 + (size_t)BATCH * 288;          // [B][576]
  float* x3 = x2 + (size_t)BATCH * 576;          // [B][144]

  unsigned short* BT2F = (unsigned short*)d_ws;  // frag-major [2][36][9][64][8]
  unsigned short* BT3F = BT2F + 331776;          // frag-major [2][9][18][64][8]
  unsigned short* BT1F = BT3F + 165888;          // frag-major [2][18][64][8]

  build_bt2f<<<1296, 256, 0, stream>>>(w2u, w2o, BT2F);
  build_bt3f<<<648, 256, 0, stream>>>(w3u, w3o, BT3F);
  build_bt1f<<<72, 256, 0, stream>>>(w1u, w1o, BT1F);

  megafused<<<BATCH / 64, 256, 0, stream>>>(inputs, BT1F, b1u, b1o, BT2F, b2u, b2o,
                                            BT3F, b3u, b3o, wd, bd, x1, x2, x3, out);
}

// Round 19
// 149.169 us; speedup vs baseline: 5.3140x; 5.3140x over previous
//
#include <hip/hip_runtime.h>

#define BATCH 65536

typedef __attribute__((ext_vector_type(8))) short bf16x8;
typedef __attribute__((ext_vector_type(4))) float f32x4;

__device__ __forceinline__ unsigned short f2bf(float f) {
  unsigned int u = __float_as_uint(f);
  u += 0x7fffu + ((u >> 16) & 1u);   // RNE (one-time weight builds only)
  return (unsigned short)(u >> 16);
}
// trunc-pack 2 floats -> 1 dword of 2 bf16 (lo in low half), single v_perm_b32
__device__ __forceinline__ unsigned pack_trunc(float lo, float hi) {
  return __builtin_amdgcn_perm(__float_as_uint(hi), __float_as_uint(lo), 0x07060302u);
}

// tanh(o)*sigmoid(u): 2 exp + 1 rcp; lower-bound clamps keep it NaN-proof.
__device__ __forceinline__ float gru_act(float u, float o) {
  u = fmaxf(u, -60.0f);
  o = fmaxf(o, -30.0f);
  float a  = __expf(-u);
  float a2 = __expf(-2.0f * o);
  return (1.0f - a2) * __builtin_amdgcn_rcpf((1.0f + a) * (1.0f + a2));
}

// conv 3x3 SAME on 3x3 grid, unrolled tap value
__device__ __forceinline__ float conv_tap(const float* __restrict__ w, int co, int ci,
                                          int p, int q, int CINTOT) {
  int pi = p / 3, pj = p % 3, qi = q / 3, qj = q % 3;
  int di = qi - pi + 1, dj = qj - pj + 1;
  if ((unsigned)di < 3u && (unsigned)dj < 3u)
    return w[((co * CINTOT + ci) * 3 + di) * 3 + dj];
  return 0.0f;
}

// Frag-major builders: lane = jc*16 + (n&15) holds B[n][kt*32 + jc*8 + s].
__global__ void build_bt2f(const float* __restrict__ wu, const float* __restrict__ wo,
                           unsigned short* __restrict__ BTF) {
  int e = blockIdx.x * 256 + threadIdx.x;
  if (e >= 331776) return;
  int g = e / 165888;
  int rem = e - g * 165888;
  int n = rem / 288, k = rem - n * 288;
  int cf = n >> 4, lr = n & 15, kt = k >> 5, jc = (k >> 3) & 3, s = k & 7;
  unsigned dst = ((((unsigned)(g * 36 + cf) * 9 + kt) * 64 + jc * 16 + lr) * 8 + s);
  BTF[dst] = f2bf(conv_tap(g ? wo : wu, n / 9, k / 9, n % 9, k % 9, 96));
}
__global__ void build_bt3f(const float* __restrict__ wu, const float* __restrict__ wo,
                           unsigned short* __restrict__ BTF) {
  int e = blockIdx.x * 256 + threadIdx.x;
  if (e >= 165888) return;
  int g = e / 82944;
  int rem = e - g * 82944;
  int n = rem / 576, k = rem - n * 576;
  int cf = n >> 4, lr = n & 15, kt = k >> 5, jc = (k >> 3) & 3, s = k & 7;
  unsigned dst = ((((unsigned)(g * 9 + cf) * 18 + kt) * 64 + jc * 16 + lr) * 8 + s);
  BTF[dst] = f2bf(conv_tap(g ? wo : wu, n / 9, k / 9, n % 9, k % 9, 80));
}
__global__ void build_bt1f(const float* __restrict__ wu, const float* __restrict__ wo,
                           unsigned short* __restrict__ BTF) {
  int e = blockIdx.x * 256 + threadIdx.x;
  if (e >= 18432) return;
  int g = e / 9216;
  int rem = e - g * 9216;
  int n = rem / 32, k = rem - n * 32;
  int cf = n >> 4, lr = n & 15, jc = (k >> 3) & 3, s = k & 7;
  unsigned dst = (((unsigned)(g * 18 + cf) * 64 + jc * 16 + lr) * 8 + s);
  float v = (k < 9) ? conv_tap(g ? wo : wu, n / 9, 0, n % 9, k, 33) : 0.0f;
  BTF[dst] = f2bf(v);
}

// ---------------- LDS layout (bytes), lifetimes barrier-separated ----------------
// Total 40960 B -> LDS permits 4 blocks/CU; VGPR(128) permits 4; residency = 4.
// [0,40960)  x1l 64x640 (L1 epi .. L2 reads)
//   overlays: xl2 [0,9216) (input staging, dead before first x1l write — ordering
//   barrier after afx reads); x3l [0,18688) (L3 epi .. dense);
//   wl [20480,25664) + blb [25664,25700); Al [25728,29824) (L3 loop)
#define OFF_X1L 0
#define OFF_X3L 0
#define OFF_XL2 0
#define OFF_WL 20480
#define OFF_BLB 25664
#define SMEM_BYTES 40960

// One L1 chunk: MFMA from register B frags, fused activation epilogue.
#define L1_CHUNK(BREG, CH) do {                                              \
    f32x4 acc1[4][2][3] = {};                                                \
    _Pragma("unroll") for (int m_ = 0; m_ < 4; ++m_)                         \
      _Pragma("unroll") for (int g_ = 0; g_ < 2; ++g_)                       \
        _Pragma("unroll") for (int f_ = 0; f_ < 3; ++f_)                     \
          acc1[m_][g_][f_] = __builtin_amdgcn_mfma_f32_16x16x32_bf16(        \
              afx[m_], BREG[g_][f_], acc1[m_][g_][f_], 0, 0, 0);             \
    _Pragma("unroll") for (int m_ = 0; m_ < 4; ++m_)                         \
      _Pragma("unroll") for (int f_ = 0; f_ < 3; ++f_) {                     \
        int n_ = (CH) * 144 + (wid * 3 + f_) * 16 + lrow;                    \
        float bU_ = b1u[n_ / 9], bO_ = b1o[n_ / 9];                          \
        f32x4 uv_ = acc1[m_][0][f_], ov_ = acc1[m_][1][f_];                  \
        _Pragma("unroll") for (int t_ = 0; t_ < 4; ++t_) {                   \
          int r_ = m_ * 16 + jc * 4 + t_;                                    \
          float v_ = gru_act(uv_[t_] + bU_, ov_[t_] + bO_);                  \
          x1[(size_t)(r0 + r_) * 288 + n_] = v_;                             \
          *(unsigned short*)(x1l + r_ * 640 + (((n_ >> 3) ^ (r_ & 7)) << 4) + (n_ & 7) * 2) = \
              (unsigned short)(__float_as_uint(v_) >> 16);                   \
        }                                                                    \
      }                                                                      \
  } while (0)

// One L2 K-step: MFMA on CUR reg B-frags; prefetch next step's frags into NXT.
#define L2_STEP(CUR, NXT, LAST) do {                                         \
    if (!(LAST)) {                                                           \
      _Pragma("unroll") for (int g_ = 0; g_ < 2; ++g_)                       \
        _Pragma("unroll") for (int f_ = 0; f_ < 3; ++f_)                     \
          NXT[g_][f_] = *(const bf16x8*)(BT2b + ldoff + offB2[g_][f_]);      \
      if (ktn == 8) { ktn = 0; ldoff += 102400u; }                           \
      else { ++ktn; ldoff += 1024u; }                                        \
    }                                                                        \
    bf16x8 af_[4];                                                           \
    const int c8_ = kt * 4 + jc;                                             \
    _Pragma("unroll") for (int m_ = 0; m_ < 4; ++m_)                         \
      af_[m_] = *(const bf16x8*)(aBase[m_] + ((c8_ ^ aXor[m_]) << 4));       \
    _Pragma("unroll") for (int m_ = 0; m_ < 4; ++m_)                         \
      _Pragma("unroll") for (int g_ = 0; g_ < 2; ++g_)                       \
        _Pragma("unroll") for (int f_ = 0; f_ < 3; ++f_)                     \
          acc[m_][g_][f_] = __builtin_amdgcn_mfma_f32_16x16x32_bf16(         \
              af_[m_], CUR[g_][f_], acc[m_][g_][f_], 0, 0, 0);               \
    if (kt == 8) {                                                           \
      _Pragma("unroll") for (int m_ = 0; m_ < 4; ++m_)                       \
        _Pragma("unroll") for (int f_ = 0; f_ < 3; ++f_) {                   \
          int n_ = n0 + (wid * 3 + f_) * 16 + lrow;                          \
          float bU_ = b2u[n_ / 9], bO_ = b2o[n_ / 9];                        \
          f32x4 uv_ = acc[m_][0][f_], ov_ = acc[m_][1][f_];                  \
          _Pragma("unroll") for (int t_ = 0; t_ < 4; ++t_) {                 \
            int r_ = r0 + m_ * 16 + jc * 4 + t_;                             \
            x2[(size_t)r_ * 576 + n_] = gru_act(uv_[t_] + bU_, ov_[t_] + bO_); \
          }                                                                  \
          acc[m_][0][f_] = (f32x4){0.f, 0.f, 0.f, 0.f};                      \
          acc[m_][1][f_] = (f32x4){0.f, 0.f, 0.f, 0.f};                      \
        }                                                                    \
      kt = 0; n0 += 192;                                                     \
    } else ++kt;                                                             \
  } while (0)

// One L3 K-step (r12/r15-proven): staged Al (2 barriers) + frag-major reg B.
#define L3_STEP(CURB, NXTB) do {                                             \
    {                                                                        \
      uint4 h_;                                                              \
      h_.x = pack_trunc(pa0.x, pa0.y);                                       \
      h_.y = pack_trunc(pa0.z, pa0.w);                                       \
      h_.z = pack_trunc(pa1.x, pa1.y);                                       \
      h_.w = pack_trunc(pa1.z, pa1.w);                                       \
      *(uint4*)wAl = h_;                                                     \
    }                                                                        \
    __syncthreads();   /* Al ready */                                        \
    if (kt3 < 17) {                                                          \
      const float* gp_ = pA + (kt3 + 1) * 32;                                \
      pa0 = *(const float4*)gp_;                                             \
      pa1 = *(const float4*)(gp_ + 4);                                       \
      if (wid < 3) {                                                         \
        _Pragma("unroll") for (int g_ = 0; g_ < 2; ++g_)                     \
          _Pragma("unroll") for (int f_ = 0; f_ < 3; ++f_)                   \
            NXTB[g_][f_] = *(const bf16x8*)(BT3b + b3ld + offB3[g_][f_]);    \
      }                                                                      \
      b3ld += 1024u;                                                         \
    }                                                                        \
    if (wid < 3) {                                                           \
      bf16x8 af_[4];                                                         \
      _Pragma("unroll") for (int m_ = 0; m_ < 4; ++m_)                       \
        af_[m_] = *(const bf16x8*)(rA3[m_]);                                 \
      _Pragma("unroll") for (int m_ = 0; m_ < 4; ++m_)                       \
        _Pragma("unroll") for (int g_ = 0; g_ < 2; ++g_)                     \
          _Pragma("unroll") for (int f_ = 0; f_ < 3; ++f_)                   \
            acc[m_][g_][f_] = __builtin_amdgcn_mfma_f32_16x16x32_bf16(       \
                af_[m_], CURB[g_][f_], acc[m_][g_][f_], 0, 0, 0);            \
    }                                                                        \
    __syncthreads();                                                         \
    ++kt3;                                                                   \
  } while (0)

__global__ __launch_bounds__(256, 2) void megafused(
    const float* __restrict__ xin, const unsigned short* __restrict__ BT1F,
    const float* __restrict__ b1u, const float* __restrict__ b1o,
    const unsigned short* __restrict__ BT2F,
    const float* __restrict__ b2u, const float* __restrict__ b2o,
    const unsigned short* __restrict__ BT3F,
    const float* __restrict__ b3u, const float* __restrict__ b3o,
    const float* __restrict__ wd, const float* __restrict__ bd,
    float* __restrict__ x1, float* __restrict__ x2,
    float* __restrict__ x3, float* __restrict__ out) {
  __shared__ __align__(16) char smem[SMEM_BYTES];
  char* x1l = smem + OFF_X1L;
  unsigned short* x3l = (unsigned short*)(smem + OFF_X3L);
  float* xl2 = (float*)(smem + OFF_XL2);    // overlays x1l[0,9216): dead pre-L1
  float* wl = (float*)(smem + OFF_WL);
  float* blb = (float*)(smem + OFF_BLB);

  const int tid = threadIdx.x;
  const int lane = tid & 63;
  const int wid = tid >> 6;
  const int lrow = lane & 15;
  const int jc = lane >> 4;
  const int r0 = blockIdx.x * 64;

  const char* BT1b = (const char*)BT1F;
  const char* BT2b = (const char*)BT2F;
  const char* BT3b = (const char*)BT3F;
  const unsigned laneB = (unsigned)lane * 16u;

  // per-thread frag-major byte offsets (wave reads its own cols, lane-contiguous)
  unsigned offB1[2][3], offB2[2][3], offB3[2][3];
#pragma unroll
  for (int g = 0; g < 2; ++g)
#pragma unroll
    for (int f = 0; f < 3; ++f) {
      offB1[g][f] = (unsigned)(g * 18 + wid * 3 + f) * 1024u + laneB;
      offB2[g][f] = (unsigned)(g * 36 + wid * 3 + f) * 9216u + laneB;
      offB3[g][f] = (unsigned)(g * 9 + wid * 3 + f) * 18432u + laneB;
    }

  // issue L1 B loads (both chunks) + L2 step-0 B loads; in flight over staging
  bf16x8 b1a[2][3], b1b[2][3], bX[2][3], bY[2][3];
  if (wid < 3) {
#pragma unroll
    for (int g = 0; g < 2; ++g)
#pragma unroll
      for (int f = 0; f < 3; ++f) {
        b1a[g][f] = *(const bf16x8*)(BT1b + offB1[g][f]);
        b1b[g][f] = *(const bf16x8*)(BT1b + 9216u + offB1[g][f]);
      }
  }
#pragma unroll
  for (int g = 0; g < 2; ++g)
#pragma unroll
    for (int f = 0; f < 3; ++f)
      bX[g][f] = *(const bf16x8*)(BT2b + offB2[g][f]);

  // stage x input into zero-padded xl2[64][36] (K padded 9->32)
  for (int c = tid; c < 2304; c += 256) {
    int row = c / 36, col = c - row * 36;
    xl2[c] = (col < 9) ? xin[(size_t)(r0 + row) * 9 + col] : 0.0f;
  }
  __syncthreads();   // xl2 visible

  // A-fragments for L1 (invariant across both chunks)
  bf16x8 afx[4];
#pragma unroll
  for (int m = 0; m < 4; ++m) {
    const float* xr = xl2 + (m * 16 + lrow) * 36 + jc * 8;
    float4 a0 = *(const float4*)xr;
    float4 a1 = *(const float4*)(xr + 4);
    union { uint4 u; bf16x8 v; } cv;
    cv.u.x = pack_trunc(a0.x, a0.y);
    cv.u.y = pack_trunc(a0.z, a0.w);
    cv.u.z = pack_trunc(a1.x, a1.y);
    cv.u.w = pack_trunc(a1.z, a1.w);
    afx[m] = cv.v;
  }
  __syncthreads();   // all xl2 reads done BEFORE x1l writes overlay the region

  // ---- L1: 2 chunks of 144 cols/gate, pure register B ----
  if (wid < 3) {
    L1_CHUNK(b1a, 0);
    L1_CHUNK(b1b, 1);
  }
  __syncthreads();   // x1l visible to all waves (LAST barrier before L2 loop)

  // ---- L2: x1l x BT2F(global->reg, coalesced frag loads). BARRIER-FREE ----
  {
    const char* aBase[4];
    int aXor[4];
#pragma unroll
    for (int m = 0; m < 4; ++m) {
      int row = m * 16 + lrow;
      aBase[m] = x1l + row * 640;
      aXor[m] = row & 7;
    }
    f32x4 acc[4][2][3] = {};
    int kt = 0, n0 = 0, ktn = 1;
    unsigned ldoff = 1024u;   // byte offset of step-1 tile (nch0, kt1)
    for (int sp = 0; sp < 13; ++sp) {
      L2_STEP(bX, bY, false);
      L2_STEP(bY, bX, false);
    }
    L2_STEP(bX, bY, true);    // step 26 (kt==8 -> final epilogue)
  }
  __syncthreads();   // x2 stores drained (vmcnt0); x1l dead beyond here

  // stage dense weights (overlay dead x1l region; disjoint from x3l)
  for (int c = tid; c < 1296; c += 256) wl[c] = wd[c];
  if (tid < 9) blb[tid] = bd[tid];

  // ---- L3: x2 (staged Al in x1l[25728..29824), 2 barriers) x BT3F reg B ----
  {
    char* Al = x1l + 25728;   // 64x64 = 4096 B, disjoint from x3l/wl/blb
    const float* pA = x2 + (size_t)(r0 + (tid >> 2)) * 576 + (tid & 3) * 8;
    char* wAl = Al + (tid >> 2) * 64 + (((tid & 3) ^ (((tid >> 2) >> 1) & 3)) << 4);
    float4 pa0 = *(const float4*)pA;
    float4 pa1 = *(const float4*)(pA + 4);
    bf16x8 b3a[2][3], b3b[2][3];
    if (wid < 3) {
#pragma unroll
      for (int g = 0; g < 2; ++g)
#pragma unroll
        for (int f = 0; f < 3; ++f)
          b3a[g][f] = *(const bf16x8*)(BT3b + offB3[g][f]);
    }
    const char* rA3[4];
#pragma unroll
    for (int m = 0; m < 4; ++m) {
      int row = m * 16 + lrow;
      rA3[m] = Al + row * 64 + ((jc ^ ((row >> 1) & 3)) << 4);
    }

    f32x4 acc[4][2][3] = {};
    int kt3 = 0;
    unsigned b3ld = 1024u;
    for (int kp = 0; kp < 9; ++kp) {
      L3_STEP(b3a, b3b);
      L3_STEP(b3b, b3a);
    }
    // epilogue: act -> x3 global fp32 + x3l (LDS bf16, trunc)
    if (wid < 3) {
#pragma unroll
      for (int m = 0; m < 4; ++m)
#pragma unroll
        for (int f = 0; f < 3; ++f) {
          int n = (wid * 3 + f) * 16 + lrow;
          float bU = b3u[n / 9], bO = b3o[n / 9];
          f32x4 uv = acc[m][0][f], ov = acc[m][1][f];
#pragma unroll
          for (int t = 0; t < 4; ++t) {
            int r = m * 16 + jc * 4 + t;
            float v = gru_act(uv[t] + bU, ov[t] + bO);
            x3[(size_t)(r0 + r) * 144 + n] = v;
            x3l[r * 146 + n] = (unsigned short)(__float_as_uint(v) >> 16);
          }
        }
    }
  }
  __syncthreads();   // x3l + wl ready

  // ---- dense head: 3 waves, 3 cols each ----
  if (wid < 3) {
    int drow = lane;
    int jb = wid * 3;
    float s0 = blb[jb], s1 = blb[jb + 1], s2 = blb[jb + 2];
    for (int k = 0; k < 144; k += 2) {
      unsigned pr = *(const unsigned*)&x3l[drow * 146 + k];
      float v0 = __uint_as_float(pr << 16);
      float v1 = __uint_as_float(pr & 0xffff0000u);
      const float2 w0 = *(const float2*)&wl[jb * 144 + k];
      const float2 w1 = *(const float2*)&wl[(jb + 1) * 144 + k];
      const float2 w2 = *(const float2*)&wl[(jb + 2) * 144 + k];
      s0 = fmaf(v0, w0.x, s0); s0 = fmaf(v1, w0.y, s0);
      s1 = fmaf(v0, w1.x, s1); s1 = fmaf(v1, w1.y, s1);
      s2 = fmaf(v0, w2.x, s2); s2 = fmaf(v1, w2.y, s2);
    }
    size_t ob = (size_t)(r0 + drow) * 9 + jb;
    out[ob] = s0; out[ob + 1] = s1; out[ob + 2] = s2;
  }
}

extern "C" void kernel_launch(void* const* d_in, const int* in_sizes, int n_in,
                              void* d_out, int out_size, void* d_ws, size_t ws_size,
                              hipStream_t stream) {
  const float* inputs = (const float*)d_in[0];
  const float* wd  = (const float*)d_in[1];
  const float* bd  = (const float*)d_in[2];
  const float* w1u = (const float*)d_in[3];
  const float* b1u = (const float*)d_in[4];
  const float* w1o = (const float*)d_in[7];
  const float* b1o = (const float*)d_in[8];
  const float* w2u = (const float*)d_in[9];
  const float* b2u = (const float*)d_in[10];
  const float* w2o = (const float*)d_in[13];
  const float* b2o = (const float*)d_in[14];
  const float* w3u = (const float*)d_in[15];
  const float* b3u = (const float*)d_in[16];
  const float* w3o = (const float*)d_in[19];
  const float* b3o = (const float*)d_in[20];

  float* out = (float*)d_out;                    // [B][9]
  float* x1 = out + (size_t)BATCH * 9;           // [B][288]
  float* x2 = x1 + (size_t)BATCH * 288;          // [B][576]
  float* x3 = x2 + (size_t)BATCH * 576;          // [B][144]

  unsigned short* BT2F = (unsigned short*)d_ws;  // frag-major [2][36][9][64][8]
  unsigned short* BT3F = BT2F + 331776;          // frag-major [2][9][18][64][8]
  unsigned short* BT1F = BT3F + 165888;          // frag-major [2][18][64][8]

  build_bt2f<<<1296, 256, 0, stream>>>(w2u, w2o, BT2F);
  build_bt3f<<<648, 256, 0, stream>>>(w3u, w3o, BT3F);
  build_bt1f<<<72, 256, 0, stream>>>(w1u, w1o, BT1F);

  megafused<<<BATCH / 64, 256, 0, stream>>>(inputs, BT1F, b1u, b1o, BT2F, b2u, b2o,
                                            BT3F, b3u, b3o, wd, bd, x1, x2, x3, out);
}

// Round 20
// 144.829 us; speedup vs baseline: 5.4732x; 1.0300x over previous
//
#include <hip/hip_runtime.h>

#define BATCH 65536

typedef __attribute__((ext_vector_type(8))) short bf16x8;
typedef __attribute__((ext_vector_type(4))) float f32x4;

__device__ __forceinline__ unsigned short f2bf(float f) {
  unsigned int u = __float_as_uint(f);
  u += 0x7fffu + ((u >> 16) & 1u);   // RNE (one-time weight builds only)
  return (unsigned short)(u >> 16);
}
// trunc-pack 2 floats -> 1 dword of 2 bf16 (lo in low half), single v_perm_b32
__device__ __forceinline__ unsigned pack_trunc(float lo, float hi) {
  return __builtin_amdgcn_perm(__float_as_uint(hi), __float_as_uint(lo), 0x07060302u);
}

// tanh(o)*sigmoid(u): 2 exp + 1 rcp; lower-bound clamps keep it NaN-proof.
__device__ __forceinline__ float gru_act(float u, float o) {
  u = fmaxf(u, -60.0f);
  o = fmaxf(o, -30.0f);
  float a  = __expf(-u);
  float a2 = __expf(-2.0f * o);
  return (1.0f - a2) * __builtin_amdgcn_rcpf((1.0f + a) * (1.0f + a2));
}

// conv 3x3 SAME on 3x3 grid, unrolled tap value
__device__ __forceinline__ float conv_tap(const float* __restrict__ w, int co, int ci,
                                          int p, int q, int CINTOT) {
  int pi = p / 3, pj = p % 3, qi = q / 3, qj = q % 3;
  int di = qi - pi + 1, dj = qj - pj + 1;
  if ((unsigned)di < 3u && (unsigned)dj < 3u)
    return w[((co * CINTOT + ci) * 3 + di) * 3 + dj];
  return 0.0f;
}

// Frag-major builders: lane = jc*16 + (n&15) holds B[n][kt*32 + jc*8 + s].
__global__ void build_bt2f(const float* __restrict__ wu, const float* __restrict__ wo,
                           unsigned short* __restrict__ BTF) {
  int e = blockIdx.x * 256 + threadIdx.x;
  if (e >= 331776) return;
  int g = e / 165888;
  int rem = e - g * 165888;
  int n = rem / 288, k = rem - n * 288;
  int cf = n >> 4, lr = n & 15, kt = k >> 5, jc = (k >> 3) & 3, s = k & 7;
  unsigned dst = ((((unsigned)(g * 36 + cf) * 9 + kt) * 64 + jc * 16 + lr) * 8 + s);
  BTF[dst] = f2bf(conv_tap(g ? wo : wu, n / 9, k / 9, n % 9, k % 9, 96));
}
__global__ void build_bt3f(const float* __restrict__ wu, const float* __restrict__ wo,
                           unsigned short* __restrict__ BTF) {
  int e = blockIdx.x * 256 + threadIdx.x;
  if (e >= 165888) return;
  int g = e / 82944;
  int rem = e - g * 82944;
  int n = rem / 576, k = rem - n * 576;
  int cf = n >> 4, lr = n & 15, kt = k >> 5, jc = (k >> 3) & 3, s = k & 7;
  unsigned dst = ((((unsigned)(g * 9 + cf) * 18 + kt) * 64 + jc * 16 + lr) * 8 + s);
  BTF[dst] = f2bf(conv_tap(g ? wo : wu, n / 9, k / 9, n % 9, k % 9, 80));
}
__global__ void build_bt1f(const float* __restrict__ wu, const float* __restrict__ wo,
                           unsigned short* __restrict__ BTF) {
  int e = blockIdx.x * 256 + threadIdx.x;
  if (e >= 18432) return;
  int g = e / 9216;
  int rem = e - g * 9216;
  int n = rem / 32, k = rem - n * 32;
  int cf = n >> 4, lr = n & 15, jc = (k >> 3) & 3, s = k & 7;
  unsigned dst = (((unsigned)(g * 18 + cf) * 64 + jc * 16 + lr) * 8 + s);
  float v = (k < 9) ? conv_tap(g ? wo : wu, n / 9, 0, n % 9, k, 33) : 0.0f;
  BTF[dst] = f2bf(v);
}

// ---------------- LDS layout (bytes), lifetimes barrier-separated ----------------
// [0,40960)     x1l 64x640 (L1 epi .. L2 reads) | x3l [0,18688) (L3 epi .. dense)
// [20480,25664) wl (post-L2 .. dense)  [25664,25700) blb   (overlay dead x1l)
// [40960,50176) xl2 64x36 f32 (pre-L1 only)
#define OFF_X1L 0
#define OFF_X3L 0
#define OFF_WL 20480
#define OFF_BLB 25664
#define OFF_XL2 40960
#define SMEM_BYTES 50176

// One L1 chunk: MFMA from register B frags, fused activation epilogue.
#define L1_CHUNK(BREG, CH) do {                                              \
    f32x4 acc1[4][2][3] = {};                                                \
    _Pragma("unroll") for (int m_ = 0; m_ < 4; ++m_)                         \
      _Pragma("unroll") for (int g_ = 0; g_ < 2; ++g_)                       \
        _Pragma("unroll") for (int f_ = 0; f_ < 3; ++f_)                     \
          acc1[m_][g_][f_] = __builtin_amdgcn_mfma_f32_16x16x32_bf16(        \
              afx[m_], BREG[g_][f_], acc1[m_][g_][f_], 0, 0, 0);             \
    _Pragma("unroll") for (int m_ = 0; m_ < 4; ++m_)                         \
      _Pragma("unroll") for (int f_ = 0; f_ < 3; ++f_) {                     \
        int n_ = (CH) * 144 + (wid * 3 + f_) * 16 + lrow;                    \
        float bU_ = b1u[n_ / 9], bO_ = b1o[n_ / 9];                          \
        f32x4 uv_ = acc1[m_][0][f_], ov_ = acc1[m_][1][f_];                  \
        _Pragma("unroll") for (int t_ = 0; t_ < 4; ++t_) {                   \
          int r_ = m_ * 16 + jc * 4 + t_;                                    \
          float v_ = gru_act(uv_[t_] + bU_, ov_[t_] + bO_);                  \
          x1[(size_t)(r0 + r_) * 288 + n_] = v_;                             \
          *(unsigned short*)(x1l + r_ * 640 + (((n_ >> 3) ^ (r_ & 7)) << 4) + (n_ & 7) * 2) = \
              (unsigned short)(__float_as_uint(v_) >> 16);                   \
        }                                                                    \
      }                                                                      \
  } while (0)

// One L2 K-step: MFMA on CUR reg B-frags; prefetch next step's frags into NXT.
#define L2_STEP(CUR, NXT, LAST) do {                                         \
    if (!(LAST)) {                                                           \
      _Pragma("unroll") for (int g_ = 0; g_ < 2; ++g_)                       \
        _Pragma("unroll") for (int f_ = 0; f_ < 3; ++f_)                     \
          NXT[g_][f_] = *(const bf16x8*)(BT2b + ldoff + offB2[g_][f_]);      \
      if (ktn == 8) { ktn = 0; ldoff += 102400u; }                           \
      else { ++ktn; ldoff += 1024u; }                                        \
    }                                                                        \
    bf16x8 af_[4];                                                           \
    const int c8_ = kt * 4 + jc;                                             \
    _Pragma("unroll") for (int m_ = 0; m_ < 4; ++m_)                         \
      af_[m_] = *(const bf16x8*)(aBase[m_] + ((c8_ ^ aXor[m_]) << 4));       \
    _Pragma("unroll") for (int m_ = 0; m_ < 4; ++m_)                         \
      _Pragma("unroll") for (int g_ = 0; g_ < 2; ++g_)                       \
        _Pragma("unroll") for (int f_ = 0; f_ < 3; ++f_)                     \
          acc[m_][g_][f_] = __builtin_amdgcn_mfma_f32_16x16x32_bf16(         \
              af_[m_], CUR[g_][f_], acc[m_][g_][f_], 0, 0, 0);               \
    if (kt == 8) {                                                           \
      _Pragma("unroll") for (int m_ = 0; m_ < 4; ++m_)                       \
        _Pragma("unroll") for (int f_ = 0; f_ < 3; ++f_) {                   \
          int n_ = n0 + (wid * 3 + f_) * 16 + lrow;                          \
          float bU_ = b2u[n_ / 9], bO_ = b2o[n_ / 9];                        \
          f32x4 uv_ = acc[m_][0][f_], ov_ = acc[m_][1][f_];                  \
          _Pragma("unroll") for (int t_ = 0; t_ < 4; ++t_) {                 \
            int r_ = r0 + m_ * 16 + jc * 4 + t_;                             \
            x2[(size_t)r_ * 576 + n_] = gru_act(uv_[t_] + bU_, ov_[t_] + bO_); \
          }                                                                  \
          acc[m_][0][f_] = (f32x4){0.f, 0.f, 0.f, 0.f};                      \
          acc[m_][1][f_] = (f32x4){0.f, 0.f, 0.f, 0.f};                      \
        }                                                                    \
      kt = 0; n0 += 192;                                                     \
    } else ++kt;                                                             \
  } while (0)

// One L3 K-step (r12-proven): staged Al (2 barriers) + frag-major reg B.
#define L3_STEP(CURB, NXTB) do {                                             \
    {                                                                        \
      uint4 h_;                                                              \
      h_.x = pack_trunc(pa0.x, pa0.y);                                       \
      h_.y = pack_trunc(pa0.z, pa0.w);                                       \
      h_.z = pack_trunc(pa1.x, pa1.y);                                       \
      h_.w = pack_trunc(pa1.z, pa1.w);                                       \
      *(uint4*)wAl = h_;                                                     \
    }                                                                        \
    __syncthreads();   /* Al ready; (kt3==0) wl/blb visible */               \
    if (kt3 < 17) {                                                          \
      const float* gp_ = pA + (kt3 + 1) * 32;                                \
      pa0 = *(const float4*)gp_;                                             \
      pa1 = *(const float4*)(gp_ + 4);                                       \
      if (wid < 3) {                                                         \
        _Pragma("unroll") for (int g_ = 0; g_ < 2; ++g_)                     \
          _Pragma("unroll") for (int f_ = 0; f_ < 3; ++f_)                   \
            NXTB[g_][f_] = *(const bf16x8*)(BT3b + b3ld + offB3[g_][f_]);    \
      }                                                                      \
      b3ld += 1024u;                                                         \
    }                                                                        \
    if (wid < 3) {                                                           \
      bf16x8 af_[4];                                                         \
      _Pragma("unroll") for (int m_ = 0; m_ < 4; ++m_)                       \
        af_[m_] = *(const bf16x8*)(rA3[m_]);                                 \
      _Pragma("unroll") for (int m_ = 0; m_ < 4; ++m_)                       \
        _Pragma("unroll") for (int g_ = 0; g_ < 2; ++g_)                     \
          _Pragma("unroll") for (int f_ = 0; f_ < 3; ++f_)                   \
            acc[m_][g_][f_] = __builtin_amdgcn_mfma_f32_16x16x32_bf16(       \
                af_[m_], CURB[g_][f_], acc[m_][g_][f_], 0, 0, 0);            \
    }                                                                        \
    __syncthreads();                                                         \
    ++kt3;                                                                   \
  } while (0)

__global__ __launch_bounds__(256, 2) void megafused(
    const float* __restrict__ xin, const unsigned short* __restrict__ BT1F,
    const float* __restrict__ b1u, const float* __restrict__ b1o,
    const unsigned short* __restrict__ BT2F,
    const float* __restrict__ b2u, const float* __restrict__ b2o,
    const unsigned short* __restrict__ BT3F,
    const float* __restrict__ b3u, const float* __restrict__ b3o,
    const float* __restrict__ wd, const float* __restrict__ bd,
    float* __restrict__ x1, float* __restrict__ x2,
    float* __restrict__ x3, float* __restrict__ out) {
  __shared__ __align__(16) char smem[SMEM_BYTES];
  char* x1l = smem + OFF_X1L;
  unsigned short* x3l = (unsigned short*)(smem + OFF_X3L);
  float* xl2 = (float*)(smem + OFF_XL2);
  float* wl = (float*)(smem + OFF_WL);
  float* blb = (float*)(smem + OFF_BLB);

  const int tid = threadIdx.x;
  const int lane = tid & 63;
  const int wid = tid >> 6;
  const int lrow = lane & 15;
  const int jc = lane >> 4;
  const int r0 = blockIdx.x * 64;

  const char* BT1b = (const char*)BT1F;
  const char* BT2b = (const char*)BT2F;
  const char* BT3b = (const char*)BT3F;
  const unsigned laneB = (unsigned)lane * 16u;

  // per-thread frag-major byte offsets (wave reads its own cols, lane-contiguous)
  unsigned offB1[2][3], offB2[2][3], offB3[2][3];
#pragma unroll
  for (int g = 0; g < 2; ++g)
#pragma unroll
    for (int f = 0; f < 3; ++f) {
      offB1[g][f] = (unsigned)(g * 18 + wid * 3 + f) * 1024u + laneB;
      offB2[g][f] = (unsigned)(g * 36 + wid * 3 + f) * 9216u + laneB;
      offB3[g][f] = (unsigned)(g * 9 + wid * 3 + f) * 18432u + laneB;
    }

  // issue L1 B loads (both chunks) + L2 step-0 B loads; in flight over staging
  bf16x8 b1a[2][3], b1b[2][3], bX[2][3], bY[2][3];
  if (wid < 3) {
#pragma unroll
    for (int g = 0; g < 2; ++g)
#pragma unroll
      for (int f = 0; f < 3; ++f) {
        b1a[g][f] = *(const bf16x8*)(BT1b + offB1[g][f]);
        b1b[g][f] = *(const bf16x8*)(BT1b + 9216u + offB1[g][f]);
      }
  }
#pragma unroll
  for (int g = 0; g < 2; ++g)
#pragma unroll
    for (int f = 0; f < 3; ++f)
      bX[g][f] = *(const bf16x8*)(BT2b + offB2[g][f]);

  // stage x input into zero-padded xl2[64][36] (K padded 9->32)
  for (int c = tid; c < 2304; c += 256) {
    int row = c / 36, col = c - row * 36;
    xl2[c] = (col < 9) ? xin[(size_t)(r0 + row) * 9 + col] : 0.0f;
  }
  __syncthreads();   // xl2 visible

  // A-fragments for L1 (invariant across both chunks)
  bf16x8 afx[4];
#pragma unroll
  for (int m = 0; m < 4; ++m) {
    const float* xr = xl2 + (m * 16 + lrow) * 36 + jc * 8;
    float4 a0 = *(const float4*)xr;
    float4 a1 = *(const float4*)(xr + 4);
    union { uint4 u; bf16x8 v; } cv;
    cv.u.x = pack_trunc(a0.x, a0.y);
    cv.u.y = pack_trunc(a0.z, a0.w);
    cv.u.z = pack_trunc(a1.x, a1.y);
    cv.u.w = pack_trunc(a1.z, a1.w);
    afx[m] = cv.v;
  }

  // ---- L1: 2 chunks of 144 cols/gate, pure register B ----
  if (wid < 3) {
    L1_CHUNK(b1a, 0);
    L1_CHUNK(b1b, 1);
  }
  __syncthreads();   // x1l visible to all waves (LAST barrier before L2 loop)

  // ---- L2: x1l x BT2F(global->reg, coalesced frag loads). BARRIER-FREE ----
  {
    const char* aBase[4];
    int aXor[4];
#pragma unroll
    for (int m = 0; m < 4; ++m) {
      int row = m * 16 + lrow;
      aBase[m] = x1l + row * 640;
      aXor[m] = row & 7;
    }
    f32x4 acc[4][2][3] = {};
    int kt = 0, n0 = 0, ktn = 1;
    unsigned ldoff = 1024u;   // byte offset of step-1 tile (nch0, kt1)
    for (int sp = 0; sp < 13; ++sp) {
      L2_STEP(bX, bY, false);
      L2_STEP(bY, bX, false);
    }
    L2_STEP(bX, bY, true);    // step 26 (kt==8 -> final epilogue)
  }
  __syncthreads();   // x2 stores drained (vmcnt0); x1l dead beyond here

  // stage dense weights (overlay dead x1l; disjoint from x3l)
  for (int c = tid; c < 1296; c += 256) wl[c] = wd[c];
  if (tid < 9) blb[tid] = bd[tid];

  // ---- L3: x2 (staged Al, 2 barriers) x BT3F(global->reg). 18 steps ----
  {
    char* Al = x1l + 25728;   // 64x64 = 4096 B, disjoint from x3l/wl/blb
    const float* pA = x2 + (size_t)(r0 + (tid >> 2)) * 576 + (tid & 3) * 8;
    char* wAl = Al + (tid >> 2) * 64 + (((tid & 3) ^ (((tid >> 2) >> 1) & 3)) << 4);
    float4 pa0 = *(const float4*)pA;
    float4 pa1 = *(const float4*)(pA + 4);
    bf16x8 b3a[2][3], b3b[2][3];
    if (wid < 3) {
#pragma unroll
      for (int g = 0; g < 2; ++g)
#pragma unroll
        for (int f = 0; f < 3; ++f)
          b3a[g][f] = *(const bf16x8*)(BT3b + offB3[g][f]);
    }
    const char* rA3[4];
#pragma unroll
    for (int m = 0; m < 4; ++m) {
      int row = m * 16 + lrow;
      rA3[m] = Al + row * 64 + ((jc ^ ((row >> 1) & 3)) << 4);
    }

    f32x4 acc[4][2][3] = {};
    int kt3 = 0;
    unsigned b3ld = 1024u;
    for (int kp = 0; kp < 9; ++kp) {
      L3_STEP(b3a, b3b);
      L3_STEP(b3b, b3a);
    }
    // epilogue: act -> x3 global fp32 + x3l (LDS bf16, trunc)
    if (wid < 3) {
#pragma unroll
      for (int m = 0; m < 4; ++m)
#pragma unroll
        for (int f = 0; f < 3; ++f) {
          int n = (wid * 3 + f) * 16 + lrow;
          float bU = b3u[n / 9], bO = b3o[n / 9];
          f32x4 uv = acc[m][0][f], ov = acc[m][1][f];
#pragma unroll
          for (int t = 0; t < 4; ++t) {
            int r = m * 16 + jc * 4 + t;
            float v = gru_act(uv[t] + bU, ov[t] + bO);
            x3[(size_t)(r0 + r) * 144 + n] = v;
            x3l[r * 146 + n] = (unsigned short)(__float_as_uint(v) >> 16);
          }
        }
    }
  }
  __syncthreads();   // x3l + wl ready

  // ---- dense head: 3 waves, 3 cols each ----
  if (wid < 3) {
    int drow = lane;
    int jb = wid * 3;
    float s0 = blb[jb], s1 = blb[jb + 1], s2 = blb[jb + 2];
    for (int k = 0; k < 144; k += 2) {
      unsigned pr = *(const unsigned*)&x3l[drow * 146 + k];
      float v0 = __uint_as_float(pr << 16);
      float v1 = __uint_as_float(pr & 0xffff0000u);
      const float2 w0 = *(const float2*)&wl[jb * 144 + k];
      const float2 w1 = *(const float2*)&wl[(jb + 1) * 144 + k];
      const float2 w2 = *(const float2*)&wl[(jb + 2) * 144 + k];
      s0 = fmaf(v0, w0.x, s0); s0 = fmaf(v1, w0.y, s0);
      s1 = fmaf(v0, w1.x, s1); s1 = fmaf(v1, w1.y, s1);
      s2 = fmaf(v0, w2.x, s2); s2 = fmaf(v1, w2.y, s2);
    }
    size_t ob = (size_t)(r0 + drow) * 9 + jb;
    out[ob] = s0; out[ob + 1] = s1; out[ob + 2] = s2;
  }
}

extern "C" void kernel_launch(void* const* d_in, const int* in_sizes, int n_in,
                              void* d_out, int out_size, void* d_ws, size_t ws_size,
                              hipStream_t stream) {
  const float* inputs = (const float*)d_in[0];
  const float* wd  = (const float*)d_in[1];
  const float* bd  = (const float*)d_in[2];
  const float* w1u = (const float*)d_in[3];
  const float* b1u = (const float*)d_in[4];
  const float* w1o = (const float*)d_in[7];
  const float* b1o = (const float*)d_in[8];
  const float* w2u = (const float*)d_in[9];
  const float* b2u = (const float*)d_in[10];
  const float* w2o = (const float*)d_in[13];
  const float* b2o = (const float*)d_in[14];
  const float* w3u = (const float*)d_in[15];
  const float* b3u = (const float*)d_in[16];
  const float* w3o = (const float*)d_in[19];
  const float* b3o = (const float*)d_in[20];

  float* out = (float*)d_out;                    // [B][9]
  float* x1 = out + (size_t)BATCH * 9;           // [B][288]
  float* x2 = x1 + (size_t)BATCH * 288;          // [B][576]
  float* x3 = x2 + (size_t)BATCH * 576;          // [B][144]

  unsigned short* BT2F = (unsigned short*)d_ws;  // frag-major [2][36][9][64][8]
  unsigned short* BT3F = BT2F + 331776;          // frag-major [2][9][18][64][8]
  unsigned short* BT1F = BT3F + 165888;          // frag-major [2][18][64][8]

  build_bt2f<<<1296, 256, 0, stream>>>(w2u, w2o, BT2F);
  build_bt3f<<<648, 256, 0, stream>>>(w3u, w3o, BT3F);
  build_bt1f<<<72, 256, 0, stream>>>(w1u, w1o, BT1F);

  megafused<<<BATCH / 64, 256, 0, stream>>>(inputs, BT1F, b1u, b1o, BT2F, b2u, b2o,
                                            BT3F, b3u, b3o, wd, bd, x1, x2, x3, out);
}